// Round 3
// baseline (339.548 us; speedup 1.0000x reference)
//
#include <hip/hip_runtime.h>

#define NPTS 32768
#define DIM 256
#define KCODES 1024
#define NSPLIT 4                 // K split across blocks
#define KSPL (KCODES / NSPLIT)   // 256 codes per split
#define BN 128                   // points per block
#define BK 128                   // codes per k-tile
#define DC 32                    // d-chunk staged in LDS
#define PAD 36                   // LDS row stride in floats (16B-aligned)
#define MARGIN 4e-3f             // fp32 top-2 gap below which we np-emulate rescore
#define RESCORE_GRID 512

// ---------------- phase 0a: fast embedding squared norms (screening only) ----------------
__global__ void enorm_kernel(const float* __restrict__ E, float* __restrict__ enorm,
                             int* __restrict__ counter) {
    if (blockIdx.x == 0 && threadIdx.x == 0) counter[0] = 0;
    int wave = threadIdx.x >> 6;
    int lane = threadIdx.x & 63;
    int k = blockIdx.x * 4 + wave;          // grid = KCODES/4 blocks
    float4 v = *(const float4*)(E + (size_t)k * DIM + lane * 4);
    float s = v.x * v.x + v.y * v.y + v.z * v.z + v.w * v.w;
#pragma unroll
    for (int m = 32; m >= 1; m >>= 1) s += __shfl_xor(s, m);
    if (lane == 0) enorm[k] = s;
}

// ---------------- phase 0b: numpy-faithful ||e||^2 (pairwise sum emulation) ----------------
// numpy pairwise for n=256: split 128+128; each 128 via 8 accumulators
// r[j] = sum_{i%8==j} a[i], combined ((r0+r1)+(r2+r3))+((r4+r5)+(r6+r7)).
__global__ void enormnp_kernel(const float* __restrict__ E, float* __restrict__ Cnp) {
#pragma clang fp contract(off)
    int k = blockIdx.x * 256 + threadIdx.x;      // grid = KCODES/256 = 4 blocks
    const float* e = E + (size_t)k * DIM;
    float half[2];
    for (int h = 0; h < 2; ++h) {
        const float* b = e + h * 128;
        float s[8];
#pragma unroll
        for (int j = 0; j < 8; ++j) { float v = b[j]; s[j] = v * v; }
        for (int i = 8; i < 128; i += 8) {
#pragma unroll
            for (int j = 0; j < 8; ++j) { float v = b[i + j]; s[j] += v * v; }
        }
        half[h] = ((s[0] + s[1]) + (s[2] + s[3])) + ((s[4] + s[5]) + (s[6] + s[7]));
    }
    Cnp[k] = half[0] + half[1];
}

// ---------------- phase 1: fp32 distances + per-split top-2 (screening) ----------------
__global__ __launch_bounds__(256, 2) void dist_kernel(
        const float* __restrict__ X, const float* __restrict__ E,
        const float* __restrict__ enorm,
        float* __restrict__ ws_minv, float* __restrict__ ws_min2,
        int* __restrict__ ws_midx) {
    __shared__ float xs[BN * PAD];
    __shared__ float es[BK * PAD];

    const int tid = threadIdx.x;
    const int ty = tid >> 4;
    const int tx = tid & 15;
    const int pbase = blockIdx.x * BN;
    const int split = blockIdx.y;

    float minv[8], min2v[8];
    int mini[8];
#pragma unroll
    for (int i = 0; i < 8; ++i) { minv[i] = 3.4e38f; min2v[i] = 3.4e38f; mini[i] = 0; }

    for (int kt = 0; kt < KSPL / BK; ++kt) {
        const int kbase = split * KSPL + kt * BK;
        float acc[8][8];
#pragma unroll
        for (int i = 0; i < 8; ++i)
#pragma unroll
            for (int j = 0; j < 8; ++j) acc[i][j] = 0.f;

        for (int dcb = 0; dcb < DIM / DC; ++dcb) {
            __syncthreads();
#pragma unroll
            for (int r = 0; r < 4; ++r) {
                int idx = r * 256 + tid;      // 0..1023
                int p = idx >> 3;             // 0..127
                int dq = idx & 7;             // 0..7 (float4 chunks of DC)
                float4 vx = *(const float4*)(X + (size_t)(pbase + p) * DIM + dcb * DC + dq * 4);
                *(float4*)(&xs[p * PAD + dq * 4]) = vx;
                float4 ve = *(const float4*)(E + (size_t)(kbase + p) * DIM + dcb * DC + dq * 4);
                *(float4*)(&es[p * PAD + dq * 4]) = ve;
            }
            __syncthreads();

            for (int d4 = 0; d4 < DC / 4; ++d4) {
                float4 ev[8];
#pragma unroll
                for (int j = 0; j < 8; ++j)
                    ev[j] = *(const float4*)(&es[(tx + j * 16) * PAD + d4 * 4]);
#pragma unroll
                for (int i = 0; i < 8; ++i) {
                    float4 xv = *(const float4*)(&xs[(ty + i * 16) * PAD + d4 * 4]);
#pragma unroll
                    for (int j = 0; j < 8; ++j) {
                        acc[i][j] += xv.x * ev[j].x;
                        acc[i][j] += xv.y * ev[j].y;
                        acc[i][j] += xv.z * ev[j].z;
                        acc[i][j] += xv.w * ev[j].w;
                    }
                }
            }
        }

#pragma unroll
        for (int j = 0; j < 8; ++j) {
            int c = kbase + tx + j * 16;
            float en = enorm[c];
#pragma unroll
            for (int i = 0; i < 8; ++i) {
                float dist = en - 2.f * acc[i][j];
                if (dist < minv[i]) {
                    min2v[i] = minv[i]; minv[i] = dist; mini[i] = c;
                } else if (dist < min2v[i]) {
                    min2v[i] = dist;
                }
            }
        }
    }

    // top-2 merge across the 16 tx lanes sharing the same points
#pragma unroll
    for (int m = 1; m < 16; m <<= 1) {
#pragma unroll
        for (int i = 0; i < 8; ++i) {
            float ov1 = __shfl_xor(minv[i], m);
            float ov2 = __shfl_xor(min2v[i], m);
            int oi1 = __shfl_xor(mini[i], m);
            if (ov1 < minv[i] || (ov1 == minv[i] && oi1 < mini[i])) {
                min2v[i] = fminf(minv[i], ov2);
                minv[i] = ov1; mini[i] = oi1;
            } else {
                min2v[i] = fminf(min2v[i], ov1);
            }
        }
    }
    if (tx == 0) {
#pragma unroll
        for (int i = 0; i < 8; ++i) {
            int p = pbase + ty + i * 16;
            ws_minv[(size_t)p * NSPLIT + split] = minv[i];
            ws_min2[(size_t)p * NSPLIT + split] = min2v[i];
            ws_midx[(size_t)p * NSPLIT + split] = mini[i];
        }
    }
}

// ---------------- phase 2: combine splits, flag ambiguous points ----------------
__global__ void resolve_kernel(const float* __restrict__ ws_minv, const float* __restrict__ ws_min2,
                               const int* __restrict__ ws_midx,
                               int* __restrict__ final_idx, int* __restrict__ list,
                               int* __restrict__ counter) {
    const int p = blockIdx.x * 256 + threadIdx.x;
    float v1 = ws_minv[(size_t)p * NSPLIT];
    float v2 = ws_min2[(size_t)p * NSPLIT];
    int i1 = ws_midx[(size_t)p * NSPLIT];
#pragma unroll
    for (int s = 1; s < NSPLIT; ++s) {
        float b1 = ws_minv[(size_t)p * NSPLIT + s];
        float b2 = ws_min2[(size_t)p * NSPLIT + s];
        int bi = ws_midx[(size_t)p * NSPLIT + s];
        if (b1 < v1 || (b1 == v1 && bi < i1)) {
            v2 = fminf(v1, b2); v1 = b1; i1 = bi;
        } else {
            v2 = fminf(v2, b1);
        }
    }
    final_idx[p] = i1;
    if (v2 - v1 <= MARGIN) {
        int slot = atomicAdd(counter, 1);
        list[slot] = p;
    }
}

// ---------------- phase 3: numpy-fp32-emulating rescore for flagged points ----------------
// Emulates: d[k] = fl32( fl32( A - 2*B[k] ) + C[k] ), argmin (first occurrence).
// A = numpy-pairwise sum of x_d^2; C = numpy-pairwise ||e||^2 (precomputed);
// B = sequential ascending-d fp32 fma chain (BLAS microkernel shape).
__global__ void rescore_np_kernel(const float* __restrict__ X, const float* __restrict__ E,
                                  const float* __restrict__ Cnp,
                                  const int* __restrict__ list, const int* __restrict__ counter,
                                  int* __restrict__ final_idx) {
#pragma clang fp contract(off)
    const int tid = threadIdx.x;
    const int cnt = counter[0];
    __shared__ float xs[DIM];
    __shared__ float sq[DIM];
    __shared__ float Ash;
    __shared__ float rv[256];
    __shared__ int ri[256];
    for (int li = blockIdx.x; li < cnt; li += gridDim.x) {
        const int p = list[li];
        __syncthreads();
        float xv = X[(size_t)p * DIM + tid];
        xs[tid] = xv;
        sq[tid] = xv * xv;
        __syncthreads();
        if (tid == 0) {
            float half[2];
            for (int h = 0; h < 2; ++h) {
                const float* b = &sq[h * 128];
                float r0 = b[0], r1 = b[1], r2 = b[2], r3 = b[3];
                float r4 = b[4], r5 = b[5], r6 = b[6], r7 = b[7];
                for (int i = 8; i < 128; i += 8) {
                    r0 += b[i + 0]; r1 += b[i + 1]; r2 += b[i + 2]; r3 += b[i + 3];
                    r4 += b[i + 4]; r5 += b[i + 5]; r6 += b[i + 6]; r7 += b[i + 7];
                }
                half[h] = ((r0 + r1) + (r2 + r3)) + ((r4 + r5) + (r6 + r7));
            }
            Ash = half[0] + half[1];
        }
        __syncthreads();
        const float A = Ash;

        const int c0 = tid * 4;             // 4 codes per thread, ascending
        float acc[4] = {0.f, 0.f, 0.f, 0.f};
        for (int d = 0; d < DIM; ++d) {
            float x = xs[d];
            acc[0] = __builtin_fmaf(x, E[(size_t)(c0 + 0) * DIM + d], acc[0]);
            acc[1] = __builtin_fmaf(x, E[(size_t)(c0 + 1) * DIM + d], acc[1]);
            acc[2] = __builtin_fmaf(x, E[(size_t)(c0 + 2) * DIM + d], acc[2]);
            acc[3] = __builtin_fmaf(x, E[(size_t)(c0 + 3) * DIM + d], acc[3]);
        }
        float bv = 3.4e38f; int bi = 1 << 30;
#pragma unroll
        for (int j = 0; j < 4; ++j) {
            float t1 = A - 2.0f * acc[j];   // 2*acc exact; one rounded subtract
            float dnp = t1 + Cnp[c0 + j];   // one rounded add (the decisive grid)
            if (dnp < bv) { bv = dnp; bi = c0 + j; }
        }
        rv[tid] = bv; ri[tid] = bi;
        __syncthreads();
        for (int s = 128; s > 0; s >>= 1) {
            if (tid < s) {
                if (rv[tid + s] < rv[tid] ||
                    (rv[tid + s] == rv[tid] && ri[tid + s] < ri[tid])) {
                    rv[tid] = rv[tid + s]; ri[tid] = ri[tid + s];
                }
            }
            __syncthreads();
        }
        if (tid == 0) final_idx[p] = ri[0];
    }
}

// ---------------- phase 4: gather, write quantized/indices, loss partials ----------------
__global__ void gather_kernel(const float* __restrict__ X, const float* __restrict__ E,
                              const int* __restrict__ final_idx,
                              float* __restrict__ out_q, float* __restrict__ out_idx,
                              float* __restrict__ ws_part) {
    const int tid = threadIdx.x;
    const int p = blockIdx.x * 16 + (tid >> 4);
    const int c = tid & 15;
    const int bi = final_idx[p];

    float ls = 0.f;
#pragma unroll
    for (int k = 0; k < 4; ++k) {
        int d4 = c + k * 16;
        float4 e4 = *(const float4*)(E + (size_t)bi * DIM + d4 * 4);
        float4 x4 = *(const float4*)(X + (size_t)p * DIM + d4 * 4);
        *(float4*)(out_q + (size_t)p * DIM + d4 * 4) = e4;
        float dx = e4.x - x4.x, dy = e4.y - x4.y, dz = e4.z - x4.z, dw = e4.w - x4.w;
        ls += dx * dx + dy * dy + dz * dz + dw * dw;
    }
    if (c == 0) out_idx[p] = (float)bi;

    __shared__ float red[256];
    red[tid] = ls;
    __syncthreads();
#pragma unroll
    for (int s = 128; s > 0; s >>= 1) {
        if (tid < s) red[tid] += red[tid + s];
        __syncthreads();
    }
    if (tid == 0) ws_part[blockIdx.x] = red[0];
}

// ---------------- phase 5: final loss reduce ----------------
__global__ void loss_kernel(const float* __restrict__ ws_part, float* __restrict__ out_loss) {
    const int tid = threadIdx.x;
    float s = 0.f;
    for (int i = tid; i < NPTS / 16; i += 256) s += ws_part[i];
    __shared__ float red[256];
    red[tid] = s;
    __syncthreads();
#pragma unroll
    for (int t = 128; t > 0; t >>= 1) {
        if (tid < t) red[tid] += red[tid + t];
        __syncthreads();
    }
    if (tid == 0)
        out_loss[0] = (1.f + 0.25f) * red[0] / (float)((size_t)NPTS * DIM);
}

extern "C" void kernel_launch(void* const* d_in, const int* in_sizes, int n_in,
                              void* d_out, int out_size, void* d_ws, size_t ws_size,
                              hipStream_t stream) {
    const float* X = (const float*)d_in[0];   // [32768, 256]
    const float* E = (const float*)d_in[1];   // [1024, 256]
    float* out = (float*)d_out;
    float* out_q = out;                                 // 8388608 floats
    float* out_loss = out + (size_t)NPTS * DIM;         // 1 float
    float* out_idx = out + (size_t)NPTS * DIM + 1;      // 32768 floats

    float* ws = (float*)d_ws;
    float* enorm = ws;                                  // 1024
    float* Cnp = enorm + KCODES;                        // 1024
    float* ws_minv = Cnp + KCODES;                      // 32768*4
    float* ws_min2 = ws_minv + (size_t)NPTS * NSPLIT;   // 32768*4
    int* ws_midx = (int*)(ws_min2 + (size_t)NPTS * NSPLIT);  // 32768*4 ints
    int* final_idx = ws_midx + (size_t)NPTS * NSPLIT;   // 32768 ints
    int* counter = final_idx + NPTS;                    // 1 int (+63 pad)
    int* list = counter + 64;                           // 32768 ints
    float* ws_part = (float*)(list + NPTS);             // 2048 floats

    enorm_kernel<<<KCODES / 4, 256, 0, stream>>>(E, enorm, counter);
    enormnp_kernel<<<KCODES / 256, 256, 0, stream>>>(E, Cnp);
    dist_kernel<<<dim3(NPTS / BN, NSPLIT), 256, 0, stream>>>(X, E, enorm,
                                                             ws_minv, ws_min2, ws_midx);
    resolve_kernel<<<NPTS / 256, 256, 0, stream>>>(ws_minv, ws_min2, ws_midx,
                                                   final_idx, list, counter);
    rescore_np_kernel<<<RESCORE_GRID, 256, 0, stream>>>(X, E, Cnp, list, counter, final_idx);
    gather_kernel<<<NPTS / 16, 256, 0, stream>>>(X, E, final_idx, out_q, out_idx, ws_part);
    loss_kernel<<<1, 256, 0, stream>>>(ws_part, out_loss);
}

// Round 4
// 253.428 us; speedup vs baseline: 1.3398x; 1.3398x over previous
//
#include <hip/hip_runtime.h>

#define NPTS 32768
#define DIM 256
#define KCODES 1024
#define NSPLIT 8                 // code-splits (128 codes per block)
#define BN 128                   // points per block
#define BKC 128                  // codes per block
#define LDSTR 40                 // LDS row stride in bf16 (80 B, conflict-free)
#define MARGIN 0.08f             // bf16 top-2 gap below which we np-emulate rescore
#define RG 8                     // rescore batch size (points per block pass)

typedef __attribute__((ext_vector_type(8))) short short8v;
typedef __attribute__((ext_vector_type(8))) unsigned short ushort8v;
typedef __attribute__((ext_vector_type(4))) float f32x4;

static __device__ __forceinline__ unsigned short f2bf(float f) {
    unsigned int u = __float_as_uint(f);
    unsigned int r = (u + 0x7fffu + ((u >> 16) & 1u)) >> 16;   // RNE
    return (unsigned short)r;
}

// ---------------- phase -1: f32 -> bf16 conversion of X and E ----------------
__global__ void convert_kernel(const float* __restrict__ X, const float* __restrict__ E,
                               unsigned short* __restrict__ Xb, unsigned short* __restrict__ Eb) {
    int i = blockIdx.x * 256 + threadIdx.x;
    size_t e8 = (size_t)i * 8;
    const float* src; unsigned short* dst; size_t off;
    if (e8 < (size_t)NPTS * DIM) { src = X; dst = Xb; off = e8; }
    else { src = E; dst = Eb; off = e8 - (size_t)NPTS * DIM; }
    float4 f0 = *(const float4*)(src + off);
    float4 f1 = *(const float4*)(src + off + 4);
    ushort8v v;
    v[0] = f2bf(f0.x); v[1] = f2bf(f0.y); v[2] = f2bf(f0.z); v[3] = f2bf(f0.w);
    v[4] = f2bf(f1.x); v[5] = f2bf(f1.y); v[6] = f2bf(f1.z); v[7] = f2bf(f1.w);
    *(ushort8v*)(dst + off) = v;
}

// ---------------- phase 0a: fast fp32 embedding norms (screening) ----------------
__global__ void enorm_kernel(const float* __restrict__ E, float* __restrict__ enorm,
                             int* __restrict__ counter) {
    if (blockIdx.x == 0 && threadIdx.x == 0) counter[0] = 0;
    int wave = threadIdx.x >> 6;
    int lane = threadIdx.x & 63;
    int k = blockIdx.x * 4 + wave;
    float4 v = *(const float4*)(E + (size_t)k * DIM + lane * 4);
    float s = v.x * v.x + v.y * v.y + v.z * v.z + v.w * v.w;
#pragma unroll
    for (int m = 32; m >= 1; m >>= 1) s += __shfl_xor(s, m);
    if (lane == 0) enorm[k] = s;
}

// ---------------- phase 0b: numpy-faithful ||e||^2 (pairwise emulation) ----------------
__global__ void enormnp_kernel(const float* __restrict__ E, float* __restrict__ Cnp) {
#pragma clang fp contract(off)
    int k = blockIdx.x * 256 + threadIdx.x;
    const float* e = E + (size_t)k * DIM;
    float half[2];
    for (int h = 0; h < 2; ++h) {
        const float* b = e + h * 128;
        float s[8];
#pragma unroll
        for (int j = 0; j < 8; ++j) { float v = b[j]; s[j] = v * v; }
        for (int i = 8; i < 128; i += 8) {
#pragma unroll
            for (int j = 0; j < 8; ++j) { float v = b[i + j]; s[j] += v * v; }
        }
        half[h] = ((s[0] + s[1]) + (s[2] + s[3])) + ((s[4] + s[5]) + (s[6] + s[7]));
    }
    Cnp[k] = half[0] + half[1];
}

// ---------------- phase 1: bf16-MFMA distance screen + per-split top-2 ----------------
// grid (NPTS/128, 8 splits), 256 threads = 4 waves (2x2). Wave (wr,wc) owns a
// 64x64 tile; 4x4 frags of mfma_f32_16x16x32_bf16.
__global__ __launch_bounds__(256, 3) void dist_kernel(
        const unsigned short* __restrict__ Xb, const unsigned short* __restrict__ Eb,
        const float* __restrict__ enorm,
        float* __restrict__ ws_minv, float* __restrict__ ws_min2,
        int* __restrict__ ws_midx) {
    __shared__ unsigned short xs[BN * LDSTR];
    __shared__ unsigned short es[BKC * LDSTR];

    const int tid = threadIdx.x;
    const int lane = tid & 63;
    const int wave = tid >> 6;
    const int wr = wave >> 1, wc = wave & 1;
    const int lg = lane >> 4, lc = lane & 15;
    const int pbase = blockIdx.x * BN;
    const int cbase = blockIdx.y * BKC;

    f32x4 acc[4][4];
#pragma unroll
    for (int i = 0; i < 4; ++i)
#pragma unroll
        for (int j = 0; j < 4; ++j) acc[i][j] = (f32x4){0.f, 0.f, 0.f, 0.f};

    const int srow = tid >> 1, shalf = tid & 1;
    for (int ks = 0; ks < DIM / 32; ++ks) {
        const int k0 = ks * 32;
        __syncthreads();
        {   // stage 128x32 bf16 of X and E (row stride 40 bf16 = 80 B)
            const unsigned short* sx = Xb + (size_t)(pbase + srow) * DIM + k0 + shalf * 16;
            ushort8v x0 = *(const ushort8v*)sx;
            ushort8v x1 = *(const ushort8v*)(sx + 8);
            *(ushort8v*)&xs[srow * LDSTR + shalf * 16] = x0;
            *(ushort8v*)&xs[srow * LDSTR + shalf * 16 + 8] = x1;
            const unsigned short* se = Eb + (size_t)(cbase + srow) * DIM + k0 + shalf * 16;
            ushort8v e0 = *(const ushort8v*)se;
            ushort8v e1 = *(const ushort8v*)(se + 8);
            *(ushort8v*)&es[srow * LDSTR + shalf * 16] = e0;
            *(ushort8v*)&es[srow * LDSTR + shalf * 16 + 8] = e1;
        }
        __syncthreads();
        short8v a[4], b[4];
#pragma unroll
        for (int f = 0; f < 4; ++f)
            a[f] = *(const short8v*)&xs[(wr * 64 + f * 16 + lc) * LDSTR + lg * 8];
#pragma unroll
        for (int f = 0; f < 4; ++f)
            b[f] = *(const short8v*)&es[(wc * 64 + f * 16 + lc) * LDSTR + lg * 8];
#pragma unroll
        for (int i = 0; i < 4; ++i)
#pragma unroll
            for (int j = 0; j < 4; ++j)
                acc[i][j] = __builtin_amdgcn_mfma_f32_16x16x32_bf16(a[i], b[j], acc[i][j], 0, 0, 0);
    }

    // epilogue: dist = ||e||^2 - 2*dot; per-point top-2 over the 128-code split.
    // C/D layout: col = lane&15 (code), row = (lane>>4)*4 + reg (point).
    float bv1[4][4], bv2[4][4]; int bi1[4][4];
#pragma unroll
    for (int i = 0; i < 4; ++i)
#pragma unroll
        for (int r = 0; r < 4; ++r) { bv1[i][r] = 3.4e38f; bv2[i][r] = 3.4e38f; bi1[i][r] = 0; }

#pragma unroll
    for (int j = 0; j < 4; ++j) {
        int cg = cbase + wc * 64 + j * 16 + lc;
        float en = enorm[cg];
#pragma unroll
        for (int i = 0; i < 4; ++i)
#pragma unroll
            for (int r = 0; r < 4; ++r) {
                float d = en - 2.f * acc[i][j][r];
                if (d < bv1[i][r]) { bv2[i][r] = bv1[i][r]; bv1[i][r] = d; bi1[i][r] = cg; }
                else if (d < bv2[i][r]) bv2[i][r] = d;
            }
    }
    // reduce across the 16 code-lanes sharing a point row
#pragma unroll
    for (int m = 1; m < 16; m <<= 1) {
#pragma unroll
        for (int i = 0; i < 4; ++i)
#pragma unroll
            for (int r = 0; r < 4; ++r) {
                float o1 = __shfl_xor(bv1[i][r], m);
                float o2 = __shfl_xor(bv2[i][r], m);
                int oi = __shfl_xor(bi1[i][r], m);
                if (o1 < bv1[i][r] || (o1 == bv1[i][r] && oi < bi1[i][r])) {
                    bv2[i][r] = fminf(bv1[i][r], o2);
                    bv1[i][r] = o1; bi1[i][r] = oi;
                } else {
                    bv2[i][r] = fminf(bv2[i][r], o1);
                }
            }
    }

    __syncthreads();                       // xs reuse as scratch
    float* sv1 = (float*)xs;               // [2][128]
    float* sv2 = sv1 + 256;
    int* si1 = (int*)(sv1 + 512);
    if (lc == 0) {
#pragma unroll
        for (int i = 0; i < 4; ++i)
#pragma unroll
            for (int r = 0; r < 4; ++r) {
                int ploc = wr * 64 + i * 16 + lg * 4 + r;
                sv1[wc * 128 + ploc] = bv1[i][r];
                sv2[wc * 128 + ploc] = bv2[i][r];
                si1[wc * 128 + ploc] = bi1[i][r];
            }
    }
    __syncthreads();
    if (tid < 128) {
        float v1 = sv1[tid], v2 = sv2[tid]; int i1 = si1[tid];
        float o1 = sv1[128 + tid], o2 = sv2[128 + tid]; int oi = si1[128 + tid];
        if (o1 < v1 || (o1 == v1 && oi < i1)) {
            v2 = fminf(v1, o2); v1 = o1; i1 = oi;
        } else {
            v2 = fminf(v2, o1);
        }
        size_t p = pbase + tid;
        ws_minv[p * NSPLIT + blockIdx.y] = v1;
        ws_min2[p * NSPLIT + blockIdx.y] = v2;
        ws_midx[p * NSPLIT + blockIdx.y] = i1;
    }
}

// ---------------- phase 2: combine splits, flag ambiguous points ----------------
__global__ void resolve_kernel(const float* __restrict__ ws_minv, const float* __restrict__ ws_min2,
                               const int* __restrict__ ws_midx,
                               int* __restrict__ final_idx, int* __restrict__ list,
                               int* __restrict__ counter) {
    const int p = blockIdx.x * 256 + threadIdx.x;
    float v1 = ws_minv[(size_t)p * NSPLIT];
    float v2 = ws_min2[(size_t)p * NSPLIT];
    int i1 = ws_midx[(size_t)p * NSPLIT];
#pragma unroll
    for (int s = 1; s < NSPLIT; ++s) {
        float b1 = ws_minv[(size_t)p * NSPLIT + s];
        float b2 = ws_min2[(size_t)p * NSPLIT + s];
        int bi = ws_midx[(size_t)p * NSPLIT + s];
        if (b1 < v1 || (b1 == v1 && bi < i1)) {
            v2 = fminf(v1, b2); v1 = b1; i1 = bi;
        } else {
            v2 = fminf(v2, b1);
        }
    }
    final_idx[p] = i1;
    if (v2 - v1 <= MARGIN) {
        int slot = atomicAdd(counter, 1);
        list[slot] = p;
    }
}

// ---------------- phase 3: numpy-fp32-emulating rescore, batched RG points ----------------
// d[k] = fl32( fl32( A - 2*B[k] ) + C[k] ); A = np-pairwise sum x^2; C = Cnp;
// B = sequential ascending-d fp32 fma chain. Identical arithmetic to the
// round-3 passing version; only batched for E-traffic amortization.
__global__ void rescore_np_kernel(const float* __restrict__ X, const float* __restrict__ E,
                                  const float* __restrict__ Cnp,
                                  const int* __restrict__ list, const int* __restrict__ counter,
                                  int* __restrict__ final_idx) {
#pragma clang fp contract(off)
    const int tid = threadIdx.x;
    const int cnt = counter[0];
    __shared__ float xs[RG][DIM];
    __shared__ float Ash[RG];
    __shared__ int plist[RG];
    __shared__ float rv[256];
    __shared__ int ri[256];
    for (int base = blockIdx.x * RG; base < cnt; base += gridDim.x * RG) {
        const int gs = min(RG, cnt - base);
        __syncthreads();
        if (tid < RG) plist[tid] = list[base + (tid < gs ? tid : gs - 1)];
        __syncthreads();
#pragma unroll
        for (int g = 0; g < RG; ++g)
            xs[g][tid] = X[(size_t)plist[g] * DIM + tid];
        __syncthreads();
        if (tid < RG) {
            float half[2];
            for (int h = 0; h < 2; ++h) {
                const float* b = &xs[tid][h * 128];
                float r0 = b[0]*b[0], r1 = b[1]*b[1], r2 = b[2]*b[2], r3 = b[3]*b[3];
                float r4 = b[4]*b[4], r5 = b[5]*b[5], r6 = b[6]*b[6], r7 = b[7]*b[7];
                for (int i = 8; i < 128; i += 8) {
                    r0 += b[i+0]*b[i+0]; r1 += b[i+1]*b[i+1];
                    r2 += b[i+2]*b[i+2]; r3 += b[i+3]*b[i+3];
                    r4 += b[i+4]*b[i+4]; r5 += b[i+5]*b[i+5];
                    r6 += b[i+6]*b[i+6]; r7 += b[i+7]*b[i+7];
                }
                half[h] = ((r0 + r1) + (r2 + r3)) + ((r4 + r5) + (r6 + r7));
            }
            Ash[tid] = half[0] + half[1];
        }
        __syncthreads();
        const int c0 = tid * 4;
        float acc[4][RG];
#pragma unroll
        for (int j = 0; j < 4; ++j)
#pragma unroll
            for (int g = 0; g < RG; ++g) acc[j][g] = 0.f;
        for (int d4 = 0; d4 < DIM; d4 += 4) {
            float4 e0 = *(const float4*)&E[(size_t)(c0 + 0) * DIM + d4];
            float4 e1 = *(const float4*)&E[(size_t)(c0 + 1) * DIM + d4];
            float4 e2 = *(const float4*)&E[(size_t)(c0 + 2) * DIM + d4];
            float4 e3 = *(const float4*)&E[(size_t)(c0 + 3) * DIM + d4];
#pragma unroll
            for (int g = 0; g < RG; ++g) {
                float4 x = *(const float4*)&xs[g][d4];
                acc[0][g] = __builtin_fmaf(x.x, e0.x, acc[0][g]);
                acc[0][g] = __builtin_fmaf(x.y, e0.y, acc[0][g]);
                acc[0][g] = __builtin_fmaf(x.z, e0.z, acc[0][g]);
                acc[0][g] = __builtin_fmaf(x.w, e0.w, acc[0][g]);
                acc[1][g] = __builtin_fmaf(x.x, e1.x, acc[1][g]);
                acc[1][g] = __builtin_fmaf(x.y, e1.y, acc[1][g]);
                acc[1][g] = __builtin_fmaf(x.z, e1.z, acc[1][g]);
                acc[1][g] = __builtin_fmaf(x.w, e1.w, acc[1][g]);
                acc[2][g] = __builtin_fmaf(x.x, e2.x, acc[2][g]);
                acc[2][g] = __builtin_fmaf(x.y, e2.y, acc[2][g]);
                acc[2][g] = __builtin_fmaf(x.z, e2.z, acc[2][g]);
                acc[2][g] = __builtin_fmaf(x.w, e2.w, acc[2][g]);
                acc[3][g] = __builtin_fmaf(x.x, e3.x, acc[3][g]);
                acc[3][g] = __builtin_fmaf(x.y, e3.y, acc[3][g]);
                acc[3][g] = __builtin_fmaf(x.z, e3.z, acc[3][g]);
                acc[3][g] = __builtin_fmaf(x.w, e3.w, acc[3][g]);
            }
        }
        float bv[RG]; int bi[RG];
#pragma unroll
        for (int g = 0; g < RG; ++g) { bv[g] = 3.4e38f; bi[g] = 1 << 30; }
#pragma unroll
        for (int j = 0; j < 4; ++j) {
            float cn = Cnp[c0 + j];
#pragma unroll
            for (int g = 0; g < RG; ++g) {
                float t1 = Ash[g] - 2.0f * acc[j][g];
                float dnp = t1 + cn;
                if (dnp < bv[g]) { bv[g] = dnp; bi[g] = c0 + j; }
            }
        }
        for (int g = 0; g < gs; ++g) {
            __syncthreads();
            rv[tid] = bv[g]; ri[tid] = bi[g];
            __syncthreads();
            for (int s = 128; s > 0; s >>= 1) {
                if (tid < s) {
                    if (rv[tid + s] < rv[tid] ||
                        (rv[tid + s] == rv[tid] && ri[tid + s] < ri[tid])) {
                        rv[tid] = rv[tid + s]; ri[tid] = ri[tid + s];
                    }
                }
                __syncthreads();
            }
            if (tid == 0) final_idx[plist[g]] = ri[0];
        }
    }
}

// ---------------- phase 4: gather, write quantized/indices, loss partials ----------------
__global__ void gather_kernel(const float* __restrict__ X, const float* __restrict__ E,
                              const int* __restrict__ final_idx,
                              float* __restrict__ out_q, float* __restrict__ out_idx,
                              float* __restrict__ ws_part) {
    const int tid = threadIdx.x;
    const int p = blockIdx.x * 16 + (tid >> 4);
    const int c = tid & 15;
    const int bi = final_idx[p];

    float ls = 0.f;
#pragma unroll
    for (int k = 0; k < 4; ++k) {
        int d4 = c + k * 16;
        float4 e4 = *(const float4*)(E + (size_t)bi * DIM + d4 * 4);
        float4 x4 = *(const float4*)(X + (size_t)p * DIM + d4 * 4);
        *(float4*)(out_q + (size_t)p * DIM + d4 * 4) = e4;
        float dx = e4.x - x4.x, dy = e4.y - x4.y, dz = e4.z - x4.z, dw = e4.w - x4.w;
        ls += dx * dx + dy * dy + dz * dz + dw * dw;
    }
    if (c == 0) out_idx[p] = (float)bi;

    __shared__ float red[256];
    red[tid] = ls;
    __syncthreads();
#pragma unroll
    for (int s = 128; s > 0; s >>= 1) {
        if (tid < s) red[tid] += red[tid + s];
        __syncthreads();
    }
    if (tid == 0) ws_part[blockIdx.x] = red[0];
}

// ---------------- phase 5: final loss reduce ----------------
__global__ void loss_kernel(const float* __restrict__ ws_part, float* __restrict__ out_loss) {
    const int tid = threadIdx.x;
    float s = 0.f;
    for (int i = tid; i < NPTS / 16; i += 256) s += ws_part[i];
    __shared__ float red[256];
    red[tid] = s;
    __syncthreads();
#pragma unroll
    for (int t = 128; t > 0; t >>= 1) {
        if (tid < t) red[tid] += red[tid + t];
        __syncthreads();
    }
    if (tid == 0)
        out_loss[0] = (1.f + 0.25f) * red[0] / (float)((size_t)NPTS * DIM);
}

extern "C" void kernel_launch(void* const* d_in, const int* in_sizes, int n_in,
                              void* d_out, int out_size, void* d_ws, size_t ws_size,
                              hipStream_t stream) {
    const float* X = (const float*)d_in[0];   // [32768, 256]
    const float* E = (const float*)d_in[1];   // [1024, 256]
    float* out = (float*)d_out;
    float* out_q = out;                                 // 8388608 floats
    float* out_loss = out + (size_t)NPTS * DIM;         // 1 float
    float* out_idx = out + (size_t)NPTS * DIM + 1;      // 32768 floats

    // bf16 staging lives inside out_q (17.3 MB < 33.5 MB); gather rewrites it all.
    unsigned short* Xb = (unsigned short*)d_out;
    unsigned short* Eb = Xb + (size_t)NPTS * DIM;

    float* ws = (float*)d_ws;
    float* enorm = ws;                                  // 1024
    float* Cnp = enorm + KCODES;                        // 1024
    float* ws_minv = Cnp + KCODES;                      // 32768*8
    float* ws_min2 = ws_minv + (size_t)NPTS * NSPLIT;   // 32768*8
    int* ws_midx = (int*)(ws_min2 + (size_t)NPTS * NSPLIT);  // 32768*8 ints
    int* final_idx = ws_midx + (size_t)NPTS * NSPLIT;   // 32768 ints
    int* counter = final_idx + NPTS;                    // 1 int (+63 pad)
    int* list = counter + 64;                           // 32768 ints
    float* ws_part = (float*)(list + NPTS);             // 2048 floats

    convert_kernel<<<(NPTS + KCODES) * DIM / 8 / 256, 256, 0, stream>>>(X, E, Xb, Eb);
    enorm_kernel<<<KCODES / 4, 256, 0, stream>>>(E, enorm, counter);
    enormnp_kernel<<<KCODES / 256, 256, 0, stream>>>(E, Cnp);
    dist_kernel<<<dim3(NPTS / BN, NSPLIT), 256, 0, stream>>>(Xb, Eb, enorm,
                                                             ws_minv, ws_min2, ws_midx);
    resolve_kernel<<<NPTS / 256, 256, 0, stream>>>(ws_minv, ws_min2, ws_midx,
                                                   final_idx, list, counter);
    rescore_np_kernel<<<1024, 256, 0, stream>>>(X, E, Cnp, list, counter, final_idx);
    gather_kernel<<<NPTS / 16, 256, 0, stream>>>(X, E, final_idx, out_q, out_idx, ws_part);
    loss_kernel<<<1, 256, 0, stream>>>(ws_part, out_loss);
}

// Round 5
// 156.034 us; speedup vs baseline: 2.1761x; 1.6242x over previous
//
#include <hip/hip_runtime.h>

#define NPTS 32768
#define DIM 256
#define KCODES 1024
#define NSPLIT 8                 // code-splits (128 codes per block)
#define BN 128                   // points per block
#define BKC 128                  // codes per block
#define LDSTR 40                 // LDS row stride in bf16 (80 B, conflict-free)
#define MARGIN 0.08f             // bf16 top-2 gap below which we np-emulate rescore
#define RG 8                     // rescore batch size (points per block pass)
#define XST 12                   // xsT row stride in floats (48 B, 16B-aligned)

typedef __attribute__((ext_vector_type(8))) short short8v;
typedef __attribute__((ext_vector_type(8))) unsigned short ushort8v;
typedef __attribute__((ext_vector_type(4))) float f32x4;

static __device__ __forceinline__ unsigned short f2bf(float f) {
    unsigned int u = __float_as_uint(f);
    unsigned int r = (u + 0x7fffu + ((u >> 16) & 1u)) >> 16;   // RNE
    return (unsigned short)r;
}

// ---------------- phase -1a: f32 -> bf16 conversion of X and E ----------------
__global__ void convert_kernel(const float* __restrict__ X, const float* __restrict__ E,
                               unsigned short* __restrict__ Xb, unsigned short* __restrict__ Eb) {
    int i = blockIdx.x * 256 + threadIdx.x;
    size_t e8 = (size_t)i * 8;
    const float* src; unsigned short* dst; size_t off;
    if (e8 < (size_t)NPTS * DIM) { src = X; dst = Xb; off = e8; }
    else { src = E; dst = Eb; off = e8 - (size_t)NPTS * DIM; }
    float4 f0 = *(const float4*)(src + off);
    float4 f1 = *(const float4*)(src + off + 4);
    ushort8v v;
    v[0] = f2bf(f0.x); v[1] = f2bf(f0.y); v[2] = f2bf(f0.z); v[3] = f2bf(f0.w);
    v[4] = f2bf(f1.x); v[5] = f2bf(f1.y); v[6] = f2bf(f1.z); v[7] = f2bf(f1.w);
    *(ushort8v*)(dst + off) = v;
}

// ---------------- phase -1b: E transpose Et[d][c] = E[c][d] (exact copy) ----------------
__global__ void etrans_kernel(const float* __restrict__ E, float* __restrict__ Et) {
    __shared__ float tile[32][33];
    const int tx = threadIdx.x & 31;          // 32
    const int ty = threadIdx.x >> 5;          // 8
    const int c0 = blockIdx.x * 32;           // code tile (1024/32 = 32)
    const int d0 = blockIdx.y * 32;           // dim tile  (256/32 = 8)
#pragma unroll
    for (int r = 0; r < 4; ++r)
        tile[ty + r * 8][tx] = E[(size_t)(c0 + ty + r * 8) * DIM + d0 + tx];
    __syncthreads();
#pragma unroll
    for (int r = 0; r < 4; ++r)
        Et[(size_t)(d0 + ty + r * 8) * KCODES + c0 + tx] = tile[tx][ty + r * 8];
}

// ---------------- phase 0a: fast fp32 embedding norms (screening) ----------------
__global__ void enorm_kernel(const float* __restrict__ E, float* __restrict__ enorm,
                             int* __restrict__ counter) {
    if (blockIdx.x == 0 && threadIdx.x == 0) counter[0] = 0;
    int wave = threadIdx.x >> 6;
    int lane = threadIdx.x & 63;
    int k = blockIdx.x * 4 + wave;
    float4 v = *(const float4*)(E + (size_t)k * DIM + lane * 4);
    float s = v.x * v.x + v.y * v.y + v.z * v.z + v.w * v.w;
#pragma unroll
    for (int m = 32; m >= 1; m >>= 1) s += __shfl_xor(s, m);
    if (lane == 0) enorm[k] = s;
}

// ---------------- phase 0b: numpy-faithful ||e||^2 (pairwise emulation) ----------------
__global__ void enormnp_kernel(const float* __restrict__ E, float* __restrict__ Cnp) {
#pragma clang fp contract(off)
    int k = blockIdx.x * 256 + threadIdx.x;
    const float* e = E + (size_t)k * DIM;
    float half[2];
    for (int h = 0; h < 2; ++h) {
        const float* b = e + h * 128;
        float s[8];
#pragma unroll
        for (int j = 0; j < 8; ++j) { float v = b[j]; s[j] = v * v; }
        for (int i = 8; i < 128; i += 8) {
#pragma unroll
            for (int j = 0; j < 8; ++j) { float v = b[i + j]; s[j] += v * v; }
        }
        half[h] = ((s[0] + s[1]) + (s[2] + s[3])) + ((s[4] + s[5]) + (s[6] + s[7]));
    }
    Cnp[k] = half[0] + half[1];
}

// ---------------- phase 1: bf16-MFMA distance screen + per-split top-2 ----------------
__global__ __launch_bounds__(256, 3) void dist_kernel(
        const unsigned short* __restrict__ Xb, const unsigned short* __restrict__ Eb,
        const float* __restrict__ enorm,
        float* __restrict__ ws_minv, float* __restrict__ ws_min2,
        int* __restrict__ ws_midx) {
    __shared__ unsigned short xs[BN * LDSTR];
    __shared__ unsigned short es[BKC * LDSTR];

    const int tid = threadIdx.x;
    const int lane = tid & 63;
    const int wave = tid >> 6;
    const int wr = wave >> 1, wc = wave & 1;
    const int lg = lane >> 4, lc = lane & 15;
    const int pbase = blockIdx.x * BN;
    const int cbase = blockIdx.y * BKC;

    f32x4 acc[4][4];
#pragma unroll
    for (int i = 0; i < 4; ++i)
#pragma unroll
        for (int j = 0; j < 4; ++j) acc[i][j] = (f32x4){0.f, 0.f, 0.f, 0.f};

    const int srow = tid >> 1, shalf = tid & 1;
    for (int ks = 0; ks < DIM / 32; ++ks) {
        const int k0 = ks * 32;
        __syncthreads();
        {
            const unsigned short* sx = Xb + (size_t)(pbase + srow) * DIM + k0 + shalf * 16;
            ushort8v x0 = *(const ushort8v*)sx;
            ushort8v x1 = *(const ushort8v*)(sx + 8);
            *(ushort8v*)&xs[srow * LDSTR + shalf * 16] = x0;
            *(ushort8v*)&xs[srow * LDSTR + shalf * 16 + 8] = x1;
            const unsigned short* se = Eb + (size_t)(cbase + srow) * DIM + k0 + shalf * 16;
            ushort8v e0 = *(const ushort8v*)se;
            ushort8v e1 = *(const ushort8v*)(se + 8);
            *(ushort8v*)&es[srow * LDSTR + shalf * 16] = e0;
            *(ushort8v*)&es[srow * LDSTR + shalf * 16 + 8] = e1;
        }
        __syncthreads();
        short8v a[4], b[4];
#pragma unroll
        for (int f = 0; f < 4; ++f)
            a[f] = *(const short8v*)&xs[(wr * 64 + f * 16 + lc) * LDSTR + lg * 8];
#pragma unroll
        for (int f = 0; f < 4; ++f)
            b[f] = *(const short8v*)&es[(wc * 64 + f * 16 + lc) * LDSTR + lg * 8];
#pragma unroll
        for (int i = 0; i < 4; ++i)
#pragma unroll
            for (int j = 0; j < 4; ++j)
                acc[i][j] = __builtin_amdgcn_mfma_f32_16x16x32_bf16(a[i], b[j], acc[i][j], 0, 0, 0);
    }

    float bv1[4][4], bv2[4][4]; int bi1[4][4];
#pragma unroll
    for (int i = 0; i < 4; ++i)
#pragma unroll
        for (int r = 0; r < 4; ++r) { bv1[i][r] = 3.4e38f; bv2[i][r] = 3.4e38f; bi1[i][r] = 0; }

#pragma unroll
    for (int j = 0; j < 4; ++j) {
        int cg = cbase + wc * 64 + j * 16 + lc;
        float en = enorm[cg];
#pragma unroll
        for (int i = 0; i < 4; ++i)
#pragma unroll
            for (int r = 0; r < 4; ++r) {
                float d = en - 2.f * acc[i][j][r];
                if (d < bv1[i][r]) { bv2[i][r] = bv1[i][r]; bv1[i][r] = d; bi1[i][r] = cg; }
                else if (d < bv2[i][r]) bv2[i][r] = d;
            }
    }
#pragma unroll
    for (int m = 1; m < 16; m <<= 1) {
#pragma unroll
        for (int i = 0; i < 4; ++i)
#pragma unroll
            for (int r = 0; r < 4; ++r) {
                float o1 = __shfl_xor(bv1[i][r], m);
                float o2 = __shfl_xor(bv2[i][r], m);
                int oi = __shfl_xor(bi1[i][r], m);
                if (o1 < bv1[i][r] || (o1 == bv1[i][r] && oi < bi1[i][r])) {
                    bv2[i][r] = fminf(bv1[i][r], o2);
                    bv1[i][r] = o1; bi1[i][r] = oi;
                } else {
                    bv2[i][r] = fminf(bv2[i][r], o1);
                }
            }
    }

    __syncthreads();
    float* sv1 = (float*)xs;
    float* sv2 = sv1 + 256;
    int* si1 = (int*)(sv1 + 512);
    if (lc == 0) {
#pragma unroll
        for (int i = 0; i < 4; ++i)
#pragma unroll
            for (int r = 0; r < 4; ++r) {
                int ploc = wr * 64 + i * 16 + lg * 4 + r;
                sv1[wc * 128 + ploc] = bv1[i][r];
                sv2[wc * 128 + ploc] = bv2[i][r];
                si1[wc * 128 + ploc] = bi1[i][r];
            }
    }
    __syncthreads();
    if (tid < 128) {
        float v1 = sv1[tid], v2 = sv2[tid]; int i1 = si1[tid];
        float o1 = sv1[128 + tid], o2 = sv2[128 + tid]; int oi = si1[128 + tid];
        if (o1 < v1 || (o1 == v1 && oi < i1)) {
            v2 = fminf(v1, o2); v1 = o1; i1 = oi;
        } else {
            v2 = fminf(v2, o1);
        }
        size_t p = pbase + tid;
        ws_minv[p * NSPLIT + blockIdx.y] = v1;
        ws_min2[p * NSPLIT + blockIdx.y] = v2;
        ws_midx[p * NSPLIT + blockIdx.y] = i1;
    }
}

// ---------------- phase 2: combine splits, flag ambiguous points ----------------
__global__ void resolve_kernel(const float* __restrict__ ws_minv, const float* __restrict__ ws_min2,
                               const int* __restrict__ ws_midx,
                               int* __restrict__ final_idx, int* __restrict__ list,
                               int* __restrict__ counter) {
    const int p = blockIdx.x * 256 + threadIdx.x;
    float v1 = ws_minv[(size_t)p * NSPLIT];
    float v2 = ws_min2[(size_t)p * NSPLIT];
    int i1 = ws_midx[(size_t)p * NSPLIT];
#pragma unroll
    for (int s = 1; s < NSPLIT; ++s) {
        float b1 = ws_minv[(size_t)p * NSPLIT + s];
        float b2 = ws_min2[(size_t)p * NSPLIT + s];
        int bi = ws_midx[(size_t)p * NSPLIT + s];
        if (b1 < v1 || (b1 == v1 && bi < i1)) {
            v2 = fminf(v1, b2); v1 = b1; i1 = bi;
        } else {
            v2 = fminf(v2, b1);
        }
    }
    final_idx[p] = i1;
    if (v2 - v1 <= MARGIN) {
        int slot = atomicAdd(counter, 1);
        list[slot] = p;
    }
}

// ---------------- phase 3: numpy-fp32-emulating rescore (coalesced via Et) ----------------
// d[k] = fl32( fl32( A - 2*B[k] ) + C[k] ); A = np-pairwise sum x^2; C = Cnp;
// B = per-lane sequential ascending-d fp32 fma chain (identical arithmetic to
// the round-3/4 passing version); Et[d][c] gives coalesced 16B/lane loads.
__global__ __launch_bounds__(256) void rescore_np_kernel(
        const float* __restrict__ X, const float* __restrict__ Et,
        const float* __restrict__ Cnp,
        const int* __restrict__ list, const int* __restrict__ counter,
        int* __restrict__ final_idx) {
#pragma clang fp contract(off)
    const int tid = threadIdx.x;
    const int lane = tid & 63;
    const int wave = tid >> 6;
    const int cnt = counter[0];
    __shared__ float xsT[DIM * XST];          // xsT[d*XST + g]
    __shared__ float Ash[RG];
    __shared__ float sA[RG][2][8];
    __shared__ int plist[RG];
    __shared__ float wv[4][RG];
    __shared__ int wi[4][RG];

    for (int base = blockIdx.x * RG; base < cnt; base += gridDim.x * RG) {
        const int gs = min(RG, cnt - base);
        __syncthreads();
        if (tid < RG) plist[tid] = list[base + (tid < gs ? tid : gs - 1)];
        __syncthreads();
        // stage x^T: xsT[d][g], d = tid
        {
            float xv[RG];
#pragma unroll
            for (int g = 0; g < RG; ++g)
                xv[g] = X[(size_t)plist[g] * DIM + tid];
#pragma unroll
            for (int g = 0; g < RG; ++g)
                xsT[tid * XST + g] = xv[g];
        }
        __syncthreads();
        // A: np-pairwise sum of x^2 — thread (g, j) computes accumulator s_j per half
        if (tid < RG * 8) {
            const int g = tid >> 3, j = tid & 7;
#pragma unroll
            for (int h = 0; h < 2; ++h) {
                float v = xsT[(h * 128 + j) * XST + g];
                float s = v * v;
                for (int i = 8; i < 128; i += 8) {
                    float w = xsT[(h * 128 + i + j) * XST + g];
                    s += w * w;
                }
                sA[g][h][j] = s;
            }
        }
        __syncthreads();
        if (tid < RG) {
            float h0 = ((sA[tid][0][0] + sA[tid][0][1]) + (sA[tid][0][2] + sA[tid][0][3]))
                     + ((sA[tid][0][4] + sA[tid][0][5]) + (sA[tid][0][6] + sA[tid][0][7]));
            float h1 = ((sA[tid][1][0] + sA[tid][1][1]) + (sA[tid][1][2] + sA[tid][1][3]))
                     + ((sA[tid][1][4] + sA[tid][1][5]) + (sA[tid][1][6] + sA[tid][1][7]));
            Ash[tid] = h0 + h1;
        }
        __syncthreads();

        // B: 4 codes per thread (c0..c0+3), RG points; ascending-d chain
        const int c0 = tid * 4;
        float acc[4][RG];
#pragma unroll
        for (int j = 0; j < 4; ++j)
#pragma unroll
            for (int g = 0; g < RG; ++g) acc[j][g] = 0.f;
#pragma unroll 4
        for (int d = 0; d < DIM; ++d) {
            float4 e4 = *(const float4*)&Et[(size_t)d * KCODES + c0];
            float4 xa = *(const float4*)&xsT[d * XST + 0];
            float4 xb = *(const float4*)&xsT[d * XST + 4];
            float xg[RG] = {xa.x, xa.y, xa.z, xa.w, xb.x, xb.y, xb.z, xb.w};
#pragma unroll
            for (int g = 0; g < RG; ++g) {
                acc[0][g] = __builtin_fmaf(xg[g], e4.x, acc[0][g]);
                acc[1][g] = __builtin_fmaf(xg[g], e4.y, acc[1][g]);
                acc[2][g] = __builtin_fmaf(xg[g], e4.z, acc[2][g]);
                acc[3][g] = __builtin_fmaf(xg[g], e4.w, acc[3][g]);
            }
        }
        float bv[RG]; int bi[RG];
#pragma unroll
        for (int g = 0; g < RG; ++g) { bv[g] = 3.4e38f; bi[g] = 1 << 30; }
#pragma unroll
        for (int j = 0; j < 4; ++j) {
            float cn = Cnp[c0 + j];
#pragma unroll
            for (int g = 0; g < RG; ++g) {
                float t1 = Ash[g] - 2.0f * acc[j][g];
                float dnp = t1 + cn;
                if (dnp < bv[g]) { bv[g] = dnp; bi[g] = c0 + j; }
            }
        }
        // wave-level (value, index) argmin, then cross-wave combine
#pragma unroll
        for (int m = 1; m < 64; m <<= 1) {
#pragma unroll
            for (int g = 0; g < RG; ++g) {
                float ov = __shfl_xor(bv[g], m);
                int oi = __shfl_xor(bi[g], m);
                if (ov < bv[g] || (ov == bv[g] && oi < bi[g])) { bv[g] = ov; bi[g] = oi; }
            }
        }
        if (lane == 0) {
#pragma unroll
            for (int g = 0; g < RG; ++g) { wv[wave][g] = bv[g]; wi[wave][g] = bi[g]; }
        }
        __syncthreads();
        if (tid < gs) {
            float v = wv[0][tid]; int i = wi[0][tid];
#pragma unroll
            for (int w = 1; w < 4; ++w) {
                float ov = wv[w][tid]; int oi = wi[w][tid];
                if (ov < v || (ov == v && oi < i)) { v = ov; i = oi; }
            }
            final_idx[plist[tid]] = i;
        }
    }
}

// ---------------- phase 4: gather, write quantized/indices, loss partials ----------------
__global__ void gather_kernel(const float* __restrict__ X, const float* __restrict__ E,
                              const int* __restrict__ final_idx,
                              float* __restrict__ out_q, float* __restrict__ out_idx,
                              float* __restrict__ ws_part) {
    const int tid = threadIdx.x;
    const int p = blockIdx.x * 16 + (tid >> 4);
    const int c = tid & 15;
    const int bi = final_idx[p];

    float ls = 0.f;
#pragma unroll
    for (int k = 0; k < 4; ++k) {
        int d4 = c + k * 16;
        float4 e4 = *(const float4*)(E + (size_t)bi * DIM + d4 * 4);
        float4 x4 = *(const float4*)(X + (size_t)p * DIM + d4 * 4);
        *(float4*)(out_q + (size_t)p * DIM + d4 * 4) = e4;
        float dx = e4.x - x4.x, dy = e4.y - x4.y, dz = e4.z - x4.z, dw = e4.w - x4.w;
        ls += dx * dx + dy * dy + dz * dz + dw * dw;
    }
    if (c == 0) out_idx[p] = (float)bi;

    __shared__ float red[256];
    red[tid] = ls;
    __syncthreads();
#pragma unroll
    for (int s = 128; s > 0; s >>= 1) {
        if (tid < s) red[tid] += red[tid + s];
        __syncthreads();
    }
    if (tid == 0) ws_part[blockIdx.x] = red[0];
}

// ---------------- phase 5: final loss reduce ----------------
__global__ void loss_kernel(const float* __restrict__ ws_part, float* __restrict__ out_loss) {
    const int tid = threadIdx.x;
    float s = 0.f;
    for (int i = tid; i < NPTS / 16; i += 256) s += ws_part[i];
    __shared__ float red[256];
    red[tid] = s;
    __syncthreads();
#pragma unroll
    for (int t = 128; t > 0; t >>= 1) {
        if (tid < t) red[tid] += red[tid + t];
        __syncthreads();
    }
    if (tid == 0)
        out_loss[0] = (1.f + 0.25f) * red[0] / (float)((size_t)NPTS * DIM);
}

extern "C" void kernel_launch(void* const* d_in, const int* in_sizes, int n_in,
                              void* d_out, int out_size, void* d_ws, size_t ws_size,
                              hipStream_t stream) {
    const float* X = (const float*)d_in[0];   // [32768, 256]
    const float* E = (const float*)d_in[1];   // [1024, 256]
    float* out = (float*)d_out;
    float* out_q = out;                                 // 8388608 floats
    float* out_loss = out + (size_t)NPTS * DIM;         // 1 float
    float* out_idx = out + (size_t)NPTS * DIM + 1;      // 32768 floats

    // staging inside out_q (rewritten by gather afterward):
    // Xb (16.8MB) + Eb (0.5MB) + Et (1MB) = 18.3MB < 33.5MB
    unsigned short* Xb = (unsigned short*)d_out;
    unsigned short* Eb = Xb + (size_t)NPTS * DIM;
    float* Et = (float*)(Eb + (size_t)KCODES * DIM);

    float* ws = (float*)d_ws;
    float* enorm = ws;                                  // 1024
    float* Cnp = enorm + KCODES;                        // 1024
    float* ws_minv = Cnp + KCODES;                      // 32768*8
    float* ws_min2 = ws_minv + (size_t)NPTS * NSPLIT;   // 32768*8
    int* ws_midx = (int*)(ws_min2 + (size_t)NPTS * NSPLIT);  // 32768*8 ints
    int* final_idx = ws_midx + (size_t)NPTS * NSPLIT;   // 32768 ints
    int* counter = final_idx + NPTS;                    // 1 int (+63 pad)
    int* list = counter + 64;                           // 32768 ints
    float* ws_part = (float*)(list + NPTS);             // 2048 floats

    convert_kernel<<<(NPTS + KCODES) * DIM / 8 / 256, 256, 0, stream>>>(X, E, Xb, Eb);
    etrans_kernel<<<dim3(KCODES / 32, DIM / 32), 256, 0, stream>>>(E, Et);
    enorm_kernel<<<KCODES / 4, 256, 0, stream>>>(E, enorm, counter);
    enormnp_kernel<<<KCODES / 256, 256, 0, stream>>>(E, Cnp);
    dist_kernel<<<dim3(NPTS / BN, NSPLIT), 256, 0, stream>>>(Xb, Eb, enorm,
                                                             ws_minv, ws_min2, ws_midx);
    resolve_kernel<<<NPTS / 256, 256, 0, stream>>>(ws_minv, ws_min2, ws_midx,
                                                   final_idx, list, counter);
    rescore_np_kernel<<<512, 256, 0, stream>>>(X, Et, Cnp, list, counter, final_idx);
    gather_kernel<<<NPTS / 16, 256, 0, stream>>>(X, E, final_idx, out_q, out_idx, ws_part);
    loss_kernel<<<1, 256, 0, stream>>>(ws_part, out_loss);
}